// Round 1
// baseline (1471.473 us; speedup 1.0000x reference)
//
#include <hip/hip_runtime.h>

#define D 128
#define TILE_M 64
#define BS_STRIDE 129   // Bs[k*129 + j] = W[j][kbase+k]; odd stride -> conflict-free transpose stage & read
#define AS_STRIDE 68    // As[m*68 + k]; 68 = 64+4 keeps float4 alignment, 2-way (free) bank aliasing

// ---------------- Stage 1: edge gather-scale-scatter (atomic) ----------------
// 32 threads per edge, 4 floats each (float4 gather, 4 fp32 atomicAdds).
__global__ __launch_bounds__(256) void edge_scatter(
    const float* __restrict__ feat, const int* __restrict__ src,
    const int* __restrict__ dst, const float* __restrict__ w,
    float* __restrict__ agg, int E)
{
    long long idx = (long long)blockIdx.x * 256 + threadIdx.x;
    int e = (int)(idx >> 5);
    if (e >= E) return;
    int c = ((int)idx & 31) << 2;

    int s = src[e];
    int d = dst[e];
    float wv = w[e];

    const float4 f = *reinterpret_cast<const float4*>(feat + (size_t)s * D + c);
    float* a = agg + (size_t)d * D + c;
    atomicAdd(a + 0, f.x * wv);
    atomicAdd(a + 1, f.y * wv);
    atomicAdd(a + 2, f.z * wv);
    atomicAdd(a + 3, f.w * wv);
}

// ---------------- Stage 2: h = relu(agg @ W^T + b) ----------------
// Block: 256 threads, 64-node x 128-out tile, K=128 done in two 64-wide passes
// (keeps LDS at ~50 KB -> 2 blocks/CU). Thread (tx in [0,16): j-dim, ty in [0,16): m-dim)
// computes 4 nodes x 8 outputs (j = tx + 16*jj -> consecutive-lane LDS reads, conflict-free).
// Safe for in-place (agg may alias out): all global reads of the tile complete
// before the barrier; stores touch only this block's rows.
__global__ __launch_bounds__(256) void node_linear_relu(
    const float* __restrict__ agg, const float* __restrict__ Wm,
    const float* __restrict__ bias, float* __restrict__ out, int N)
{
    __shared__ float Bs[64 * BS_STRIDE];      // 33024 B
    __shared__ float As[TILE_M * AS_STRIDE];  // 17408 B

    const int tid = threadIdx.x;
    const int tx = tid & 15;
    const int ty = tid >> 4;
    const int node0 = blockIdx.x * TILE_M;

    float acc[4][8];
#pragma unroll
    for (int i = 0; i < 4; ++i)
#pragma unroll
        for (int jj = 0; jj < 8; ++jj) acc[i][jj] = 0.0f;

    for (int kh = 0; kh < 2; ++kh) {
        const int kbase = kh * 64;

        // stage W^T slice: Bs[k][j] = W[j][kbase+k]
        for (int i = tid; i < 128 * 64; i += 256) {
            int j = i >> 6;
            int k = i & 63;
            Bs[k * BS_STRIDE + j] = Wm[j * 128 + kbase + k];
        }
        // stage A slice
        for (int i = tid; i < TILE_M * 64; i += 256) {
            int m = i >> 6;
            int k = i & 63;
            int n = node0 + m;
            As[m * AS_STRIDE + k] = (n < N) ? agg[(size_t)n * D + kbase + k] : 0.0f;
        }
        __syncthreads();

        for (int k0 = 0; k0 < 64; k0 += 4) {
            float a[4][4];
#pragma unroll
            for (int i = 0; i < 4; ++i) {
                const float4 v = *reinterpret_cast<const float4*>(
                    &As[(ty * 4 + i) * AS_STRIDE + k0]);
                a[i][0] = v.x; a[i][1] = v.y; a[i][2] = v.z; a[i][3] = v.w;
            }
#pragma unroll
            for (int kk = 0; kk < 4; ++kk) {
                float bv[8];
#pragma unroll
                for (int jj = 0; jj < 8; ++jj)
                    bv[jj] = Bs[(k0 + kk) * BS_STRIDE + tx + 16 * jj];
#pragma unroll
                for (int i = 0; i < 4; ++i)
#pragma unroll
                    for (int jj = 0; jj < 8; ++jj)
                        acc[i][jj] += a[i][kk] * bv[jj];
            }
        }
        __syncthreads();  // before restaging / stores
    }

    float bv[8];
#pragma unroll
    for (int jj = 0; jj < 8; ++jj) bv[jj] = bias[tx + 16 * jj];

#pragma unroll
    for (int i = 0; i < 4; ++i) {
        int n = node0 + ty * 4 + i;
        if (n < N) {
            float* o = out + (size_t)n * D;
#pragma unroll
            for (int jj = 0; jj < 8; ++jj) {
                float v = acc[i][jj] + bv[jj];
                o[tx + 16 * jj] = v > 0.0f ? v : 0.0f;
            }
        }
    }
}

extern "C" void kernel_launch(void* const* d_in, const int* in_sizes, int n_in,
                              void* d_out, int out_size, void* d_ws, size_t ws_size,
                              hipStream_t stream) {
    const float* feat = (const float*)d_in[0];
    const int*   src  = (const int*)d_in[1];
    const int*   dst  = (const int*)d_in[2];
    const float* w    = (const float*)d_in[3];
    const float* Wm   = (const float*)d_in[4];
    const float* bias = (const float*)d_in[5];
    float* out = (float*)d_out;

    const int N = in_sizes[0] / D;   // 50000
    const int E = in_sizes[1];       // 800000

    const size_t agg_bytes = (size_t)N * D * sizeof(float);
    // Use workspace for the accumulator if it's big enough; otherwise alias
    // into d_out (node_linear_relu is in-place safe).
    float* agg = (ws_size >= agg_bytes) ? (float*)d_ws : out;

    hipMemsetAsync(agg, 0, agg_bytes, stream);

    long long scatter_threads = (long long)E * 32;
    int scatter_blocks = (int)((scatter_threads + 255) / 256);
    edge_scatter<<<scatter_blocks, 256, 0, stream>>>(feat, src, dst, w, agg, E);

    int gemm_blocks = (N + TILE_M - 1) / TILE_M;
    node_linear_relu<<<gemm_blocks, 256, 0, stream>>>(agg, Wm, bias, out, N);
}

// Round 2
// 286.803 us; speedup vs baseline: 5.1306x; 5.1306x over previous
//
#include <hip/hip_runtime.h>

#define D 128
#define TILE_M 64
#define BS_STRIDE 129   // Bs[k*129 + j]: odd stride -> conflict-free transpose stage & read
#define AS_STRIDE 68    // As[m*68 + k]: keeps float4 alignment, 2-way (free) bank aliasing

// ---------------- GEMM: out = in @ W^T (+ bias, relu if EPI) ----------------
// 256 threads, 64-row x 128-col tile, K=128 in two 64-wide passes (~50KB LDS).
// In-place safe (in may alias out): tile fully staged into LDS before stores.
template<bool EPI>
__global__ __launch_bounds__(256) void node_linear(
    const float* __restrict__ in, const float* __restrict__ Wm,
    const float* __restrict__ bias, float* __restrict__ out, int N)
{
    __shared__ float Bs[64 * BS_STRIDE];
    __shared__ float As[TILE_M * AS_STRIDE];

    const int tid = threadIdx.x;
    const int tx = tid & 15;
    const int ty = tid >> 4;
    const int node0 = blockIdx.x * TILE_M;

    float acc[4][8];
#pragma unroll
    for (int i = 0; i < 4; ++i)
#pragma unroll
        for (int jj = 0; jj < 8; ++jj) acc[i][jj] = 0.0f;

    for (int kh = 0; kh < 2; ++kh) {
        const int kbase = kh * 64;
        for (int i = tid; i < 128 * 64; i += 256) {
            int j = i >> 6;
            int k = i & 63;
            Bs[k * BS_STRIDE + j] = Wm[j * 128 + kbase + k];
        }
        for (int i = tid; i < TILE_M * 64; i += 256) {
            int m = i >> 6;
            int k = i & 63;
            int n = node0 + m;
            As[m * AS_STRIDE + k] = (n < N) ? in[(size_t)n * D + kbase + k] : 0.0f;
        }
        __syncthreads();

        for (int k0 = 0; k0 < 64; k0 += 4) {
            float a[4][4];
#pragma unroll
            for (int i = 0; i < 4; ++i) {
                const float4 v = *reinterpret_cast<const float4*>(
                    &As[(ty * 4 + i) * AS_STRIDE + k0]);
                a[i][0] = v.x; a[i][1] = v.y; a[i][2] = v.z; a[i][3] = v.w;
            }
#pragma unroll
            for (int kk = 0; kk < 4; ++kk) {
                float bv[8];
#pragma unroll
                for (int jj = 0; jj < 8; ++jj)
                    bv[jj] = Bs[(k0 + kk) * BS_STRIDE + tx + 16 * jj];
#pragma unroll
                for (int i = 0; i < 4; ++i)
#pragma unroll
                    for (int jj = 0; jj < 8; ++jj)
                        acc[i][jj] += a[i][kk] * bv[jj];
            }
        }
        __syncthreads();
    }

    float bv[8];
#pragma unroll
    for (int jj = 0; jj < 8; ++jj) bv[jj] = EPI ? bias[tx + 16 * jj] : 0.0f;

#pragma unroll
    for (int i = 0; i < 4; ++i) {
        int n = node0 + ty * 4 + i;
        if (n < N) {
            float* o = out + (size_t)n * D;
#pragma unroll
            for (int jj = 0; jj < 8; ++jj) {
                float v = acc[i][jj] + bv[jj];
                o[tx + 16 * jj] = EPI ? (v > 0.0f ? v : 0.0f) : v;
            }
        }
    }
}

// ---------------- CSR build ----------------
__global__ __launch_bounds__(256) void edge_hist(
    const int* __restrict__ dst, int* __restrict__ counts, int E)
{
    int e = blockIdx.x * 256 + threadIdx.x;
    if (e < E) atomicAdd(&counts[dst[e]], 1);
}

// per-1024-chunk exclusive scan + chunk totals
__global__ __launch_bounds__(256) void scan_partial(
    const int* __restrict__ counts, int* __restrict__ offs,
    int* __restrict__ bsum, int N)
{
    __shared__ int s[256];
    const int tid = threadIdx.x;
    const int base = blockIdx.x * 1024 + tid * 4;
    int c0 = (base + 0 < N) ? counts[base + 0] : 0;
    int c1 = (base + 1 < N) ? counts[base + 1] : 0;
    int c2 = (base + 2 < N) ? counts[base + 2] : 0;
    int c3 = (base + 3 < N) ? counts[base + 3] : 0;
    int t = c0 + c1 + c2 + c3;
    s[tid] = t;
    __syncthreads();
    for (int off = 1; off < 256; off <<= 1) {
        int add = (tid >= off) ? s[tid - off] : 0;
        __syncthreads();
        s[tid] += add;
        __syncthreads();
    }
    int excl = s[tid] - t;
    if (base + 0 < N) offs[base + 0] = excl;
    if (base + 1 < N) offs[base + 1] = excl + c0;
    if (base + 2 < N) offs[base + 2] = excl + c0 + c1;
    if (base + 3 < N) offs[base + 3] = excl + c0 + c1 + c2;
    if (tid == 255) bsum[blockIdx.x] = s[255];
}

// single-block exclusive scan of chunk totals (chunked, arbitrary NB)
__global__ void scan_block_sums(const int* __restrict__ bsum,
                                int* __restrict__ boff, int NB)
{
    __shared__ int s[64];
    const int tid = threadIdx.x;  // 64 threads
    int carry = 0;
    for (int b = 0; b < NB; b += 64) {
        int i = b + tid;
        int v = (i < NB) ? bsum[i] : 0;
        s[tid] = v;
        __syncthreads();
        for (int off = 1; off < 64; off <<= 1) {
            int add = (tid >= off) ? s[tid - off] : 0;
            __syncthreads();
            s[tid] += add;
            __syncthreads();
        }
        int incl = s[tid];
        int tot = s[63];
        if (i < NB) boff[i] = carry + incl - v;
        __syncthreads();
        carry += tot;
    }
}

__global__ __launch_bounds__(256) void add_block_offsets(
    int* __restrict__ offs, const int* __restrict__ boff, int N, int E)
{
    int i = blockIdx.x * 256 + threadIdx.x;
    if (i < N) offs[i] += boff[i >> 10];
    if (i == N) offs[N] = E;
}

__global__ __launch_bounds__(256) void edge_bucket(
    const int* __restrict__ src, const int* __restrict__ dst,
    const float* __restrict__ w, int* __restrict__ cursor,
    int* __restrict__ esrc, float* __restrict__ ewt, int E)
{
    int e = blockIdx.x * 256 + threadIdx.x;
    if (e >= E) return;
    int d = dst[e];
    int pos = atomicAdd(&cursor[d], 1);
    esrc[pos] = src[e];
    ewt[pos] = w[e];
}

// ---------------- gather-reduce: out[n] = [relu](sum_e w_e * tfeat[src_e] [+ b]) --------
// half-wave (32 lanes) per node, float4 per lane.
template<bool EPI>
__global__ __launch_bounds__(256) void csr_gather(
    const float* __restrict__ tfeat, const int* __restrict__ esrc,
    const float* __restrict__ ewt, const int* __restrict__ offs,
    const float* __restrict__ bias, float* __restrict__ out, int N)
{
    int node = blockIdx.x * 8 + (threadIdx.x >> 5);
    if (node >= N) return;
    const int lane = threadIdx.x & 31;
    const int c = lane << 2;
    int i = offs[node];
    const int end = offs[node + 1];
    float ax = 0.f, ay = 0.f, az = 0.f, aw = 0.f;
    for (; i + 1 < end; i += 2) {
        int s0 = esrc[i], s1 = esrc[i + 1];
        float w0 = ewt[i], w1 = ewt[i + 1];
        const float4 f0 = *reinterpret_cast<const float4*>(tfeat + (size_t)s0 * D + c);
        const float4 f1 = *reinterpret_cast<const float4*>(tfeat + (size_t)s1 * D + c);
        ax += f0.x * w0; ay += f0.y * w0; az += f0.z * w0; aw += f0.w * w0;
        ax += f1.x * w1; ay += f1.y * w1; az += f1.z * w1; aw += f1.w * w1;
    }
    if (i < end) {
        int s0 = esrc[i];
        float w0 = ewt[i];
        const float4 f0 = *reinterpret_cast<const float4*>(tfeat + (size_t)s0 * D + c);
        ax += f0.x * w0; ay += f0.y * w0; az += f0.z * w0; aw += f0.w * w0;
    }
    float4 r;
    if (EPI) {
        const float4 bv = *reinterpret_cast<const float4*>(bias + c);
        r.x = fmaxf(ax + bv.x, 0.f);
        r.y = fmaxf(ay + bv.y, 0.f);
        r.z = fmaxf(az + bv.z, 0.f);
        r.w = fmaxf(aw + bv.w, 0.f);
    } else {
        r.x = ax; r.y = ay; r.z = az; r.w = aw;
    }
    *reinterpret_cast<float4*>(out + (size_t)node * D + c) = r;
}

// ---------------- tier-1 fallback: atomic scatter ----------------
__global__ __launch_bounds__(256) void edge_scatter(
    const float* __restrict__ feat, const int* __restrict__ src,
    const int* __restrict__ dst, const float* __restrict__ w,
    float* __restrict__ agg, int E)
{
    long long idx = (long long)blockIdx.x * 256 + threadIdx.x;
    int e = (int)(idx >> 5);
    if (e >= E) return;
    int c = ((int)idx & 31) << 2;
    int s = src[e];
    int d = dst[e];
    float wv = w[e];
    const float4 f = *reinterpret_cast<const float4*>(feat + (size_t)s * D + c);
    float* a = agg + (size_t)d * D + c;
    atomicAdd(a + 0, f.x * wv);
    atomicAdd(a + 1, f.y * wv);
    atomicAdd(a + 2, f.z * wv);
    atomicAdd(a + 3, f.w * wv);
}

extern "C" void kernel_launch(void* const* d_in, const int* in_sizes, int n_in,
                              void* d_out, int out_size, void* d_ws, size_t ws_size,
                              hipStream_t stream) {
    const float* feat = (const float*)d_in[0];
    const int*   src  = (const int*)d_in[1];
    const int*   dst  = (const int*)d_in[2];
    const float* w    = (const float*)d_in[3];
    const float* Wm   = (const float*)d_in[4];
    const float* bias = (const float*)d_in[5];
    float* out = (float*)d_out;

    const int N = in_sizes[0] / D;   // 50000
    const int E = in_sizes[1];       // 800000
    const int NB = (N + 1023) / 1024;

    const size_t tfeat_b = (size_t)N * D * sizeof(float);
    const size_t esrc_b  = (size_t)E * sizeof(int);
    const size_t ewt_b   = (size_t)E * sizeof(float);
    const size_t offs_b  = (size_t)(N + 1) * sizeof(int);
    const size_t cnt_b   = (size_t)N * sizeof(int);
    const size_t bsum_b  = (size_t)(NB + 1) * sizeof(int);
    auto align_up = [](size_t x) { return (x + 255) & ~(size_t)255; };

    const size_t need_csr  = align_up(esrc_b) + align_up(ewt_b) + align_up(offs_b)
                           + align_up(cnt_b) + 2 * align_up(bsum_b);
    const size_t need_full = need_csr + align_up(tfeat_b);

    const int gemm_blocks = (N + TILE_M - 1) / TILE_M;

    if (ws_size >= need_csr) {
        char* p = (char*)d_ws;
        int*   esrc   = (int*)p;            p += align_up(esrc_b);
        float* ewt    = (float*)p;          p += align_up(ewt_b);
        int*   offs   = (int*)p;            p += align_up(offs_b);
        int*   cnt    = (int*)p;            p += align_up(cnt_b);   // counts, then cursor
        int*   bsum   = (int*)p;            p += align_up(bsum_b);
        int*   boff   = (int*)p;            p += align_up(bsum_b);
        bool full = (ws_size >= need_full);
        float* tfeat  = full ? (float*)p : out;

        // CSR build
        hipMemsetAsync(cnt, 0, cnt_b, stream);
        edge_hist<<<(E + 255) / 256, 256, 0, stream>>>(dst, cnt, E);
        scan_partial<<<NB, 256, 0, stream>>>(cnt, offs, bsum, N);
        scan_block_sums<<<1, 64, 0, stream>>>(bsum, boff, NB);
        add_block_offsets<<<(N + 256) / 256, 256, 0, stream>>>(offs, boff, N, E);
        hipMemcpyAsync(cnt, offs, cnt_b, hipMemcpyDeviceToDevice, stream);  // cursor = offs
        edge_bucket<<<(E + 255) / 256, 256, 0, stream>>>(src, dst, w, cnt, esrc, ewt, E);

        if (full) {
            // transform first (linearity), then fused gather+bias+relu -> out
            node_linear<false><<<gemm_blocks, 256, 0, stream>>>(feat, Wm, bias, tfeat, N);
            csr_gather<true><<<(N + 7) / 8, 256, 0, stream>>>(tfeat, esrc, ewt, offs, bias, out, N);
        } else {
            // aggregate raw features into out, then in-place linear+bias+relu
            csr_gather<false><<<(N + 7) / 8, 256, 0, stream>>>(feat, esrc, ewt, offs, bias, out, N);
            node_linear<true><<<gemm_blocks, 256, 0, stream>>>(out, Wm, bias, out, N);
        }
    } else {
        // tier-1 fallback: atomic scatter into out, in-place linear
        hipMemsetAsync(out, 0, tfeat_b, stream);
        long long st = (long long)E * 32;
        edge_scatter<<<(int)((st + 255) / 256), 256, 0, stream>>>(feat, src, dst, w, out, E);
        node_linear<true><<<gemm_blocks, 256, 0, stream>>>(out, Wm, bias, out, N);
    }
}

// Round 3
// 237.706 us; speedup vs baseline: 6.1903x; 1.2065x over previous
//
#include <hip/hip_runtime.h>

#define D 128
#define TILE_M 64
#define BS_STRIDE 129
#define AS_STRIDE 68

typedef __attribute__((ext_vector_type(8))) short short8;
typedef __attribute__((ext_vector_type(4))) float floatx4;

__device__ __forceinline__ unsigned short f2bf(float f) {
    unsigned u = __float_as_uint(f);
    u += 0x7fffu + ((u >> 16) & 1u);   // round-to-nearest-even
    return (unsigned short)(u >> 16);
}

// ---------------- cast W (128x128 fp32 -> bf16) ----------------
__global__ __launch_bounds__(256) void cast_w(
    const float* __restrict__ Wm, unsigned short* __restrict__ Wb)
{
    int i = blockIdx.x * 256 + threadIdx.x;
    if (i < D * D) Wb[i] = f2bf(Wm[i]);
}

// ---------------- MFMA GEMM: tf(bf16) = feat(fp32->bf16) @ W^T ----------------
// 4 waves/block; wave w handles rows [m0+16w, m0+16w+16) x all 128 cols.
// A-frag: lane holds A[m0+(lane&15)][kt*32 + (lane>>4)*8 + j], j=0..7 (fp32 load + RTN cast).
// B-frag: lane holds W[nt*16+(lane&15)][kt*32 + (lane>>4)*8 + j] (bf16 direct 16B load).
// C/D:    acc[nt][r] = D[m0w + (lane>>4)*4 + r][nt*16 + (lane&15)].
__global__ __launch_bounds__(256) void gemm_bf16(
    const float* __restrict__ feat, const unsigned short* __restrict__ Wb,
    unsigned short* __restrict__ tf, int N)
{
    const int lane = threadIdx.x & 63;
    const int wave = threadIdx.x >> 6;
    const int m0 = blockIdx.x * 64 + wave * 16;
    const int mr = m0 + (lane & 15);
    const int kq = (lane >> 4) * 8;

    const float* arow = feat + (size_t)(mr < N ? mr : (N - 1)) * D + kq;

    short8 a[4];
#pragma unroll
    for (int kt = 0; kt < 4; ++kt) {
        const float* p = arow + kt * 32;
        const float4 lo = *reinterpret_cast<const float4*>(p);
        const float4 hi = *reinterpret_cast<const float4*>(p + 4);
        short8 v;
        v[0] = (short)f2bf(lo.x); v[1] = (short)f2bf(lo.y);
        v[2] = (short)f2bf(lo.z); v[3] = (short)f2bf(lo.w);
        v[4] = (short)f2bf(hi.x); v[5] = (short)f2bf(hi.y);
        v[6] = (short)f2bf(hi.z); v[7] = (short)f2bf(hi.w);
        a[kt] = v;
    }

    floatx4 acc[8];
#pragma unroll
    for (int nt = 0; nt < 8; ++nt) {
        acc[nt][0] = 0.f; acc[nt][1] = 0.f; acc[nt][2] = 0.f; acc[nt][3] = 0.f;
    }

#pragma unroll
    for (int nt = 0; nt < 8; ++nt) {
        const unsigned short* brow = Wb + (size_t)(nt * 16 + (lane & 15)) * D + kq;
#pragma unroll
        for (int kt = 0; kt < 4; ++kt) {
            short8 b = *reinterpret_cast<const short8*>(brow + kt * 32);
            acc[nt] = __builtin_amdgcn_mfma_f32_16x16x32_bf16(a[kt], b, acc[nt], 0, 0, 0);
        }
    }

    const int orow = m0 + (lane >> 4) * 4;
    const int col = lane & 15;
#pragma unroll
    for (int r = 0; r < 4; ++r) {
        int m = orow + r;
        if (m < N) {
            unsigned short* o = tf + (size_t)m * D + col;
#pragma unroll
            for (int nt = 0; nt < 8; ++nt)
                o[nt * 16] = f2bf(acc[nt][r]);
        }
    }
}

// ---------------- CSR build ----------------
__global__ __launch_bounds__(256) void edge_hist(
    const int* __restrict__ dst, int* __restrict__ counts, int E)
{
    int e = blockIdx.x * 256 + threadIdx.x;
    if (e < E) atomicAdd(&counts[dst[e]], 1);
}

__global__ __launch_bounds__(256) void scan_partial(
    const int* __restrict__ counts, int* __restrict__ offs,
    int* __restrict__ bsum, int N)
{
    __shared__ int s[256];
    const int tid = threadIdx.x;
    const int base = blockIdx.x * 1024 + tid * 4;
    int c0 = (base + 0 < N) ? counts[base + 0] : 0;
    int c1 = (base + 1 < N) ? counts[base + 1] : 0;
    int c2 = (base + 2 < N) ? counts[base + 2] : 0;
    int c3 = (base + 3 < N) ? counts[base + 3] : 0;
    int t = c0 + c1 + c2 + c3;
    s[tid] = t;
    __syncthreads();
    for (int off = 1; off < 256; off <<= 1) {
        int add = (tid >= off) ? s[tid - off] : 0;
        __syncthreads();
        s[tid] += add;
        __syncthreads();
    }
    int excl = s[tid] - t;
    if (base + 0 < N) offs[base + 0] = excl;
    if (base + 1 < N) offs[base + 1] = excl + c0;
    if (base + 2 < N) offs[base + 2] = excl + c0 + c1;
    if (base + 3 < N) offs[base + 3] = excl + c0 + c1 + c2;
    if (tid == 255) bsum[blockIdx.x] = s[255];
}

__global__ void scan_block_sums(const int* __restrict__ bsum,
                                int* __restrict__ boff, int NB)
{
    __shared__ int s[64];
    const int tid = threadIdx.x;  // 64 threads
    int carry = 0;
    for (int b = 0; b < NB; b += 64) {
        int i = b + tid;
        int v = (i < NB) ? bsum[i] : 0;
        s[tid] = v;
        __syncthreads();
        for (int off = 1; off < 64; off <<= 1) {
            int add = (tid >= off) ? s[tid - off] : 0;
            __syncthreads();
            s[tid] += add;
            __syncthreads();
        }
        int incl = s[tid];
        int tot = s[63];
        if (i < NB) boff[i] = carry + incl - v;
        __syncthreads();
        carry += tot;
    }
}

__global__ __launch_bounds__(256) void add_block_offsets(
    int* __restrict__ offs, const int* __restrict__ boff, int N, int E)
{
    int i = blockIdx.x * 256 + threadIdx.x;
    if (i < N) offs[i] += boff[i >> 10];
    if (i == N) offs[N] = E;
}

// bucket scatter: single 8B packed store per edge {src, w-bits}
__global__ __launch_bounds__(256) void edge_bucket(
    const int* __restrict__ src, const int* __restrict__ dst,
    const float* __restrict__ w, int* __restrict__ cursor,
    int2* __restrict__ epack, int E)
{
    int e = blockIdx.x * 256 + threadIdx.x;
    if (e >= E) return;
    int d = dst[e];
    int pos = atomicAdd(&cursor[d], 1);
    epack[pos] = make_int2(src[e], __float_as_int(w[e]));
}

// ---------------- gather-reduce over bf16 tfeat: out = relu(sum w*tf[src] + b) ---------
__global__ __launch_bounds__(256) void csr_gather_bf16(
    const unsigned short* __restrict__ tf, const int2* __restrict__ ep,
    const int* __restrict__ offs, const float* __restrict__ bias,
    float* __restrict__ out, int N)
{
    int node = blockIdx.x * 8 + (threadIdx.x >> 5);
    if (node >= N) return;
    const int lane = threadIdx.x & 31;
    const int c = lane << 2;
    int i = offs[node];
    const int end = offs[node + 1];
    float a0 = 0.f, a1 = 0.f, a2 = 0.f, a3 = 0.f;
    for (; i + 1 < end; i += 2) {
        int2 e0 = ep[i];
        int2 e1 = ep[i + 1];
        float w0 = __int_as_float(e0.y);
        float w1 = __int_as_float(e1.y);
        uint2 q0 = *reinterpret_cast<const uint2*>(tf + (size_t)e0.x * D + c);
        uint2 q1 = *reinterpret_cast<const uint2*>(tf + (size_t)e1.x * D + c);
        a0 += __uint_as_float(q0.x << 16) * w0;
        a1 += __uint_as_float(q0.x & 0xffff0000u) * w0;
        a2 += __uint_as_float(q0.y << 16) * w0;
        a3 += __uint_as_float(q0.y & 0xffff0000u) * w0;
        a0 += __uint_as_float(q1.x << 16) * w1;
        a1 += __uint_as_float(q1.x & 0xffff0000u) * w1;
        a2 += __uint_as_float(q1.y << 16) * w1;
        a3 += __uint_as_float(q1.y & 0xffff0000u) * w1;
    }
    if (i < end) {
        int2 e0 = ep[i];
        float w0 = __int_as_float(e0.y);
        uint2 q0 = *reinterpret_cast<const uint2*>(tf + (size_t)e0.x * D + c);
        a0 += __uint_as_float(q0.x << 16) * w0;
        a1 += __uint_as_float(q0.x & 0xffff0000u) * w0;
        a2 += __uint_as_float(q0.y << 16) * w0;
        a3 += __uint_as_float(q0.y & 0xffff0000u) * w0;
    }
    const float4 bv = *reinterpret_cast<const float4*>(bias + c);
    float4 r;
    r.x = fmaxf(a0 + bv.x, 0.f);
    r.y = fmaxf(a1 + bv.y, 0.f);
    r.z = fmaxf(a2 + bv.z, 0.f);
    r.w = fmaxf(a3 + bv.w, 0.f);
    *reinterpret_cast<float4*>(out + (size_t)node * D + c) = r;
}

// ---------------- fp32 gather (fallback path, reads fp32 rows) ----------------
__global__ __launch_bounds__(256) void csr_gather_f32(
    const float* __restrict__ feat, const int2* __restrict__ ep,
    const int* __restrict__ offs, float* __restrict__ out, int N)
{
    int node = blockIdx.x * 8 + (threadIdx.x >> 5);
    if (node >= N) return;
    const int lane = threadIdx.x & 31;
    const int c = lane << 2;
    int i = offs[node];
    const int end = offs[node + 1];
    float a0 = 0.f, a1 = 0.f, a2 = 0.f, a3 = 0.f;
    for (; i < end; ++i) {
        int2 e0 = ep[i];
        float w0 = __int_as_float(e0.y);
        const float4 f = *reinterpret_cast<const float4*>(feat + (size_t)e0.x * D + c);
        a0 += f.x * w0; a1 += f.y * w0; a2 += f.z * w0; a3 += f.w * w0;
    }
    float4 r; r.x = a0; r.y = a1; r.z = a2; r.w = a3;
    *reinterpret_cast<float4*>(out + (size_t)node * D + c) = r;
}

// ---------------- fp32 vector GEMM (fallback): out = relu(in @ W^T + b), in-place safe ----
__global__ __launch_bounds__(256) void node_linear(
    const float* __restrict__ in, const float* __restrict__ Wm,
    const float* __restrict__ bias, float* __restrict__ out, int N)
{
    __shared__ float Bs[64 * BS_STRIDE];
    __shared__ float As[TILE_M * AS_STRIDE];
    const int tid = threadIdx.x;
    const int tx = tid & 15;
    const int ty = tid >> 4;
    const int node0 = blockIdx.x * TILE_M;
    float acc[4][8];
#pragma unroll
    for (int i = 0; i < 4; ++i)
#pragma unroll
        for (int jj = 0; jj < 8; ++jj) acc[i][jj] = 0.0f;
    for (int kh = 0; kh < 2; ++kh) {
        const int kbase = kh * 64;
        for (int i = tid; i < 128 * 64; i += 256) {
            int j = i >> 6, k = i & 63;
            Bs[k * BS_STRIDE + j] = Wm[j * 128 + kbase + k];
        }
        for (int i = tid; i < TILE_M * 64; i += 256) {
            int m = i >> 6, k = i & 63;
            int n = node0 + m;
            As[m * AS_STRIDE + k] = (n < N) ? in[(size_t)n * D + kbase + k] : 0.0f;
        }
        __syncthreads();
        for (int k0 = 0; k0 < 64; k0 += 4) {
            float a[4][4];
#pragma unroll
            for (int i = 0; i < 4; ++i) {
                const float4 v = *reinterpret_cast<const float4*>(&As[(ty * 4 + i) * AS_STRIDE + k0]);
                a[i][0] = v.x; a[i][1] = v.y; a[i][2] = v.z; a[i][3] = v.w;
            }
#pragma unroll
            for (int kk = 0; kk < 4; ++kk) {
                float bv[8];
#pragma unroll
                for (int jj = 0; jj < 8; ++jj) bv[jj] = Bs[(k0 + kk) * BS_STRIDE + tx + 16 * jj];
#pragma unroll
                for (int i = 0; i < 4; ++i)
#pragma unroll
                    for (int jj = 0; jj < 8; ++jj) acc[i][jj] += a[i][kk] * bv[jj];
            }
        }
        __syncthreads();
    }
    float bv[8];
#pragma unroll
    for (int jj = 0; jj < 8; ++jj) bv[jj] = bias[tx + 16 * jj];
#pragma unroll
    for (int i = 0; i < 4; ++i) {
        int n = node0 + ty * 4 + i;
        if (n < N) {
            float* o = out + (size_t)n * D;
#pragma unroll
            for (int jj = 0; jj < 8; ++jj) {
                float v = acc[i][jj] + bv[jj];
                o[tx + 16 * jj] = v > 0.0f ? v : 0.0f;
            }
        }
    }
}

// ---------------- tier-1 fallback: atomic scatter ----------------
__global__ __launch_bounds__(256) void edge_scatter(
    const float* __restrict__ feat, const int* __restrict__ src,
    const int* __restrict__ dst, const float* __restrict__ w,
    float* __restrict__ agg, int E)
{
    long long idx = (long long)blockIdx.x * 256 + threadIdx.x;
    int e = (int)(idx >> 5);
    if (e >= E) return;
    int c = ((int)idx & 31) << 2;
    int s = src[e];
    int d = dst[e];
    float wv = w[e];
    const float4 f = *reinterpret_cast<const float4*>(feat + (size_t)s * D + c);
    float* a = agg + (size_t)d * D + c;
    atomicAdd(a + 0, f.x * wv);
    atomicAdd(a + 1, f.y * wv);
    atomicAdd(a + 2, f.z * wv);
    atomicAdd(a + 3, f.w * wv);
}

extern "C" void kernel_launch(void* const* d_in, const int* in_sizes, int n_in,
                              void* d_out, int out_size, void* d_ws, size_t ws_size,
                              hipStream_t stream) {
    const float* feat = (const float*)d_in[0];
    const int*   src  = (const int*)d_in[1];
    const int*   dst  = (const int*)d_in[2];
    const float* w    = (const float*)d_in[3];
    const float* Wm   = (const float*)d_in[4];
    const float* bias = (const float*)d_in[5];
    float* out = (float*)d_out;

    const int N = in_sizes[0] / D;   // 50000
    const int E = in_sizes[1];       // 800000
    const int NB = (N + 1023) / 1024;

    const size_t ep_b   = (size_t)E * 8;
    const size_t offs_b = (size_t)(N + 1) * sizeof(int);
    const size_t cnt_b  = (size_t)N * sizeof(int);
    const size_t bsum_b = (size_t)(NB + 1) * sizeof(int);
    const size_t wb_b   = (size_t)D * D * 2;
    const size_t tf_b   = (size_t)N * D * 2;
    auto align_up = [](size_t x) { return (x + 255) & ~(size_t)255; };

    const size_t need_csr  = align_up(ep_b) + align_up(offs_b) + align_up(cnt_b)
                           + 2 * align_up(bsum_b);
    const size_t need_full = need_csr + align_up(wb_b) + align_up(tf_b);

    const int gemm_blocks_f32 = (N + TILE_M - 1) / TILE_M;

    if (ws_size >= need_csr) {
        char* p = (char*)d_ws;
        int2*  ep   = (int2*)p;  p += align_up(ep_b);
        int*   offs = (int*)p;   p += align_up(offs_b);
        int*   cnt  = (int*)p;   p += align_up(cnt_b);
        int*   bsum = (int*)p;   p += align_up(bsum_b);
        int*   boff = (int*)p;   p += align_up(bsum_b);
        const bool full = (ws_size >= need_full);
        unsigned short* Wb = (unsigned short*)p;  p += align_up(wb_b);
        unsigned short* tf = (unsigned short*)p;

        // CSR build
        hipMemsetAsync(cnt, 0, cnt_b, stream);
        edge_hist<<<(E + 255) / 256, 256, 0, stream>>>(dst, cnt, E);
        scan_partial<<<NB, 256, 0, stream>>>(cnt, offs, bsum, N);
        scan_block_sums<<<1, 64, 0, stream>>>(bsum, boff, NB);
        add_block_offsets<<<(N + 256) / 256, 256, 0, stream>>>(offs, boff, N, E);
        hipMemcpyAsync(cnt, offs, cnt_b, hipMemcpyDeviceToDevice, stream);  // cursor
        edge_bucket<<<(E + 255) / 256, 256, 0, stream>>>(src, dst, w, cnt, ep, E);

        if (full) {
            // transform-first (linearity): tf = bf16(feat @ W^T), then fused gather+bias+relu
            cast_w<<<(D * D + 255) / 256, 256, 0, stream>>>(Wm, Wb);
            gemm_bf16<<<(N + 63) / 64, 256, 0, stream>>>(feat, Wb, tf, N);
            csr_gather_bf16<<<(N + 7) / 8, 256, 0, stream>>>(tf, ep, offs, bias, out, N);
        } else {
            csr_gather_f32<<<(N + 7) / 8, 256, 0, stream>>>(feat, ep, offs, out, N);
            node_linear<<<gemm_blocks_f32, 256, 0, stream>>>(out, Wm, bias, out, N);
        }
    } else {
        hipMemsetAsync(out, 0, (size_t)N * D * sizeof(float), stream);
        long long st = (long long)E * 32;
        edge_scatter<<<(int)((st + 255) / 256), 256, 0, stream>>>(feat, src, dst, w, out, E);
        node_linear<<<gemm_blocks_f32, 256, 0, stream>>>(out, Wm, bias, out, N);
    }
}

// Round 4
// 212.788 us; speedup vs baseline: 6.9152x; 1.1171x over previous
//
#include <hip/hip_runtime.h>

#define D 128
#define TILE_M 64
#define BS_STRIDE 129
#define AS_STRIDE 68
#define WS_STRIDE 136   // shorts; 272 B rows -> 16 B aligned, banks spread

typedef __attribute__((ext_vector_type(8))) short short8;
typedef __attribute__((ext_vector_type(4))) float floatx4;
typedef __attribute__((ext_vector_type(4))) unsigned short ushortx4;

__device__ __forceinline__ unsigned short f2bf(float f) {
    unsigned u = __float_as_uint(f);
    u += 0x7fffu + ((u >> 16) & 1u);   // round-to-nearest-even
    return (unsigned short)(u >> 16);
}

// ---------------- MFMA GEMM: tf(bf16) = feat(fp32->bf16) @ W^T ----------------
// W staged fp32->bf16 into LDS by each block (replaces separate cast_w kernel).
// 4 waves/block; wave w: rows [m0+16w, m0+16w+16) x 128 cols via 16x16x32 MFMA.
__global__ __launch_bounds__(256) void gemm_bf16(
    const float* __restrict__ feat, const float* __restrict__ Wm,
    unsigned short* __restrict__ tf, int N)
{
    __shared__ unsigned short Ws[128 * WS_STRIDE];

    const int tid = threadIdx.x;
    // stage W: 4096 float4s, 16 per thread
    for (int idx = tid; idx < 128 * 128 / 4; idx += 256) {
        int r = idx >> 5;
        int c = (idx & 31) * 4;
        const float4 v = reinterpret_cast<const float4*>(Wm)[idx];
        ushortx4 s;
        s[0] = f2bf(v.x); s[1] = f2bf(v.y); s[2] = f2bf(v.z); s[3] = f2bf(v.w);
        *reinterpret_cast<ushortx4*>(&Ws[r * WS_STRIDE + c]) = s;
    }

    const int lane = tid & 63;
    const int wave = tid >> 6;
    const int m0 = blockIdx.x * 64 + wave * 16;
    const int mr = m0 + (lane & 15);
    const int kq = (lane >> 4) * 8;

    const float* arow = feat + (size_t)(mr < N ? mr : (N - 1)) * D + kq;

    short8 a[4];
#pragma unroll
    for (int kt = 0; kt < 4; ++kt) {
        const float* p = arow + kt * 32;
        const float4 lo = *reinterpret_cast<const float4*>(p);
        const float4 hi = *reinterpret_cast<const float4*>(p + 4);
        short8 v;
        v[0] = (short)f2bf(lo.x); v[1] = (short)f2bf(lo.y);
        v[2] = (short)f2bf(lo.z); v[3] = (short)f2bf(lo.w);
        v[4] = (short)f2bf(hi.x); v[5] = (short)f2bf(hi.y);
        v[6] = (short)f2bf(hi.z); v[7] = (short)f2bf(hi.w);
        a[kt] = v;
    }

    __syncthreads();

    floatx4 acc[8];
#pragma unroll
    for (int nt = 0; nt < 8; ++nt) {
        acc[nt][0] = 0.f; acc[nt][1] = 0.f; acc[nt][2] = 0.f; acc[nt][3] = 0.f;
    }

#pragma unroll
    for (int nt = 0; nt < 8; ++nt) {
        const unsigned short* brow = &Ws[(nt * 16 + (lane & 15)) * WS_STRIDE + kq];
#pragma unroll
        for (int kt = 0; kt < 4; ++kt) {
            short8 b = *reinterpret_cast<const short8*>(brow + kt * 32);
            acc[nt] = __builtin_amdgcn_mfma_f32_16x16x32_bf16(a[kt], b, acc[nt], 0, 0, 0);
        }
    }

    const int orow = m0 + (lane >> 4) * 4;
    const int col = lane & 15;
#pragma unroll
    for (int r = 0; r < 4; ++r) {
        int m = orow + r;
        if (m < N) {
            unsigned short* o = tf + (size_t)m * D + col;
#pragma unroll
            for (int nt = 0; nt < 8; ++nt)
                o[nt * 16] = f2bf(acc[nt][r]);
        }
    }
}

// ---------------- CSR build ----------------
__global__ __launch_bounds__(256) void edge_hist(
    const int* __restrict__ dst, int* __restrict__ counts, int E)
{
    int e4 = (blockIdx.x * 256 + threadIdx.x) * 4;
    if (e4 + 3 < E) {
        const int4 d = *reinterpret_cast<const int4*>(dst + e4);
        atomicAdd(&counts[d.x], 1);
        atomicAdd(&counts[d.y], 1);
        atomicAdd(&counts[d.z], 1);
        atomicAdd(&counts[d.w], 1);
    } else {
        for (int e = e4; e < E; ++e) atomicAdd(&counts[dst[e]], 1);
    }
}

__global__ __launch_bounds__(256) void scan_partial(
    const int* __restrict__ counts, int* __restrict__ offs,
    int* __restrict__ bsum, int N)
{
    __shared__ int s[256];
    const int tid = threadIdx.x;
    const int base = blockIdx.x * 1024 + tid * 4;
    int c0 = (base + 0 < N) ? counts[base + 0] : 0;
    int c1 = (base + 1 < N) ? counts[base + 1] : 0;
    int c2 = (base + 2 < N) ? counts[base + 2] : 0;
    int c3 = (base + 3 < N) ? counts[base + 3] : 0;
    int t = c0 + c1 + c2 + c3;
    s[tid] = t;
    __syncthreads();
    for (int off = 1; off < 256; off <<= 1) {
        int add = (tid >= off) ? s[tid - off] : 0;
        __syncthreads();
        s[tid] += add;
        __syncthreads();
    }
    int excl = s[tid] - t;
    if (base + 0 < N) offs[base + 0] = excl;
    if (base + 1 < N) offs[base + 1] = excl + c0;
    if (base + 2 < N) offs[base + 2] = excl + c0 + c1;
    if (base + 3 < N) offs[base + 3] = excl + c0 + c1 + c2;
    if (tid == 255) bsum[blockIdx.x] = s[255];
}

__global__ void scan_block_sums(const int* __restrict__ bsum,
                                int* __restrict__ boff, int NB)
{
    __shared__ int s[64];
    const int tid = threadIdx.x;  // 64 threads
    int carry = 0;
    for (int b = 0; b < NB; b += 64) {
        int i = b + tid;
        int v = (i < NB) ? bsum[i] : 0;
        s[tid] = v;
        __syncthreads();
        for (int off = 1; off < 64; off <<= 1) {
            int add = (tid >= off) ? s[tid - off] : 0;
            __syncthreads();
            s[tid] += add;
            __syncthreads();
        }
        int incl = s[tid];
        int tot = s[63];
        if (i < NB) boff[i] = carry + incl - v;
        __syncthreads();
        carry += tot;
    }
}

// also initializes the bucket cursor (replaces d2d copy)
__global__ __launch_bounds__(256) void add_block_offsets(
    int* __restrict__ offs, const int* __restrict__ boff,
    int* __restrict__ cursor, int N, int E)
{
    int i = blockIdx.x * 256 + threadIdx.x;
    if (i < N) {
        int v = offs[i] + boff[i >> 10];
        offs[i] = v;
        cursor[i] = v;
    }
    if (i == N) offs[N] = E;
}

// ---------------- XCD-range-owned bucket scatter ----------------
// Role xcd = blockIdx&7; each role scans ALL edges, writes only dst in its
// N/8 range. On round-robin block->XCD dispatch, all stores to a given epack
// line come from one XCD's L2 -> dirty lines merge (kills the 64B/store
// writeback amplification). Correct regardless of actual block->XCD mapping.
__global__ __launch_bounds__(256) void edge_bucket_x8(
    const int* __restrict__ src, const int* __restrict__ dst,
    const float* __restrict__ w, int* __restrict__ cursor,
    int2* __restrict__ epack, int E, int N)
{
    const int xcd = blockIdx.x & 7;
    const int blk = blockIdx.x >> 3;
    const int nblk = gridDim.x >> 3;
    const int lo = (int)((long long)xcd * N / 8);
    const int hi = (int)((long long)(xcd + 1) * N / 8);
    for (int e = blk * 256 + threadIdx.x; e < E; e += nblk * 256) {
        int d = dst[e];
        if (d >= lo && d < hi) {
            int pos = atomicAdd(&cursor[d], 1);
            epack[pos] = make_int2(src[e], __float_as_int(w[e]));
        }
    }
}

// ---------------- gather-reduce over bf16 tfeat: out = relu(sum w*tf[src] + b) ---------
__global__ __launch_bounds__(256) void csr_gather_bf16(
    const unsigned short* __restrict__ tf, const int2* __restrict__ ep,
    const int* __restrict__ offs, const float* __restrict__ bias,
    float* __restrict__ out, int N)
{
    int node = blockIdx.x * 8 + (threadIdx.x >> 5);
    if (node >= N) return;
    const int lane = threadIdx.x & 31;
    const int c = lane << 2;
    int i = offs[node];
    const int end = offs[node + 1];
    float a0 = 0.f, a1 = 0.f, a2 = 0.f, a3 = 0.f;

#define ACC(Q, W)                                        \
    a0 += __uint_as_float((Q).x << 16) * (W);            \
    a1 += __uint_as_float((Q).x & 0xffff0000u) * (W);    \
    a2 += __uint_as_float((Q).y << 16) * (W);            \
    a3 += __uint_as_float((Q).y & 0xffff0000u) * (W);

    for (; i + 3 < end; i += 4) {
        int2 e0 = ep[i], e1 = ep[i + 1], e2 = ep[i + 2], e3 = ep[i + 3];
        uint2 q0 = *reinterpret_cast<const uint2*>(tf + (size_t)e0.x * D + c);
        uint2 q1 = *reinterpret_cast<const uint2*>(tf + (size_t)e1.x * D + c);
        uint2 q2 = *reinterpret_cast<const uint2*>(tf + (size_t)e2.x * D + c);
        uint2 q3 = *reinterpret_cast<const uint2*>(tf + (size_t)e3.x * D + c);
        float w0 = __int_as_float(e0.y), w1 = __int_as_float(e1.y);
        float w2 = __int_as_float(e2.y), w3 = __int_as_float(e3.y);
        ACC(q0, w0) ACC(q1, w1) ACC(q2, w2) ACC(q3, w3)
    }
    for (; i < end; ++i) {
        int2 e0 = ep[i];
        float w0 = __int_as_float(e0.y);
        uint2 q0 = *reinterpret_cast<const uint2*>(tf + (size_t)e0.x * D + c);
        ACC(q0, w0)
    }
#undef ACC

    const float4 bv = *reinterpret_cast<const float4*>(bias + c);
    float4 r;
    r.x = fmaxf(a0 + bv.x, 0.f);
    r.y = fmaxf(a1 + bv.y, 0.f);
    r.z = fmaxf(a2 + bv.z, 0.f);
    r.w = fmaxf(a3 + bv.w, 0.f);
    *reinterpret_cast<float4*>(out + (size_t)node * D + c) = r;
}

// ---------------- fp32 gather (fallback path) ----------------
__global__ __launch_bounds__(256) void csr_gather_f32(
    const float* __restrict__ feat, const int2* __restrict__ ep,
    const int* __restrict__ offs, float* __restrict__ out, int N)
{
    int node = blockIdx.x * 8 + (threadIdx.x >> 5);
    if (node >= N) return;
    const int lane = threadIdx.x & 31;
    const int c = lane << 2;
    int i = offs[node];
    const int end = offs[node + 1];
    float a0 = 0.f, a1 = 0.f, a2 = 0.f, a3 = 0.f;
    for (; i < end; ++i) {
        int2 e0 = ep[i];
        float w0 = __int_as_float(e0.y);
        const float4 f = *reinterpret_cast<const float4*>(feat + (size_t)e0.x * D + c);
        a0 += f.x * w0; a1 += f.y * w0; a2 += f.z * w0; a3 += f.w * w0;
    }
    float4 r; r.x = a0; r.y = a1; r.z = a2; r.w = a3;
    *reinterpret_cast<float4*>(out + (size_t)node * D + c) = r;
}

// ---------------- fp32 vector GEMM (fallback): out = relu(in @ W^T + b) ----
__global__ __launch_bounds__(256) void node_linear(
    const float* __restrict__ in, const float* __restrict__ Wm,
    const float* __restrict__ bias, float* __restrict__ out, int N)
{
    __shared__ float Bs[64 * BS_STRIDE];
    __shared__ float As[TILE_M * AS_STRIDE];
    const int tid = threadIdx.x;
    const int tx = tid & 15;
    const int ty = tid >> 4;
    const int node0 = blockIdx.x * TILE_M;
    float acc[4][8];
#pragma unroll
    for (int i = 0; i < 4; ++i)
#pragma unroll
        for (int jj = 0; jj < 8; ++jj) acc[i][jj] = 0.0f;
    for (int kh = 0; kh < 2; ++kh) {
        const int kbase = kh * 64;
        for (int i = tid; i < 128 * 64; i += 256) {
            int j = i >> 6, k = i & 63;
            Bs[k * BS_STRIDE + j] = Wm[j * 128 + kbase + k];
        }
        for (int i = tid; i < TILE_M * 64; i += 256) {
            int m = i >> 6, k = i & 63;
            int n = node0 + m;
            As[m * AS_STRIDE + k] = (n < N) ? in[(size_t)n * D + kbase + k] : 0.0f;
        }
        __syncthreads();
        for (int k0 = 0; k0 < 64; k0 += 4) {
            float a[4][4];
#pragma unroll
            for (int i = 0; i < 4; ++i) {
                const float4 v = *reinterpret_cast<const float4*>(&As[(ty * 4 + i) * AS_STRIDE + k0]);
                a[i][0] = v.x; a[i][1] = v.y; a[i][2] = v.z; a[i][3] = v.w;
            }
#pragma unroll
            for (int kk = 0; kk < 4; ++kk) {
                float bv[8];
#pragma unroll
                for (int jj = 0; jj < 8; ++jj) bv[jj] = Bs[(k0 + kk) * BS_STRIDE + tx + 16 * jj];
#pragma unroll
                for (int i = 0; i < 4; ++i)
#pragma unroll
                    for (int jj = 0; jj < 8; ++jj) acc[i][jj] += a[i][kk] * bv[jj];
            }
        }
        __syncthreads();
    }
    float bv[8];
#pragma unroll
    for (int jj = 0; jj < 8; ++jj) bv[jj] = bias[tx + 16 * jj];
#pragma unroll
    for (int i = 0; i < 4; ++i) {
        int n = node0 + ty * 4 + i;
        if (n < N) {
            float* o = out + (size_t)n * D;
#pragma unroll
            for (int jj = 0; jj < 8; ++jj) {
                float v = acc[i][jj] + bv[jj];
                o[tx + 16 * jj] = v > 0.0f ? v : 0.0f;
            }
        }
    }
}

// ---------------- tier-1 fallback: atomic scatter ----------------
__global__ __launch_bounds__(256) void edge_scatter(
    const float* __restrict__ feat, const int* __restrict__ src,
    const int* __restrict__ dst, const float* __restrict__ w,
    float* __restrict__ agg, int E)
{
    long long idx = (long long)blockIdx.x * 256 + threadIdx.x;
    int e = (int)(idx >> 5);
    if (e >= E) return;
    int c = ((int)idx & 31) << 2;
    int s = src[e];
    int d = dst[e];
    float wv = w[e];
    const float4 f = *reinterpret_cast<const float4*>(feat + (size_t)s * D + c);
    float* a = agg + (size_t)d * D + c;
    atomicAdd(a + 0, f.x * wv);
    atomicAdd(a + 1, f.y * wv);
    atomicAdd(a + 2, f.z * wv);
    atomicAdd(a + 3, f.w * wv);
}

extern "C" void kernel_launch(void* const* d_in, const int* in_sizes, int n_in,
                              void* d_out, int out_size, void* d_ws, size_t ws_size,
                              hipStream_t stream) {
    const float* feat = (const float*)d_in[0];
    const int*   src  = (const int*)d_in[1];
    const int*   dst  = (const int*)d_in[2];
    const float* w    = (const float*)d_in[3];
    const float* Wm   = (const float*)d_in[4];
    const float* bias = (const float*)d_in[5];
    float* out = (float*)d_out;

    const int N = in_sizes[0] / D;   // 50000
    const int E = in_sizes[1];       // 800000
    const int NB = (N + 1023) / 1024;

    const size_t ep_b   = (size_t)E * 8;
    const size_t offs_b = (size_t)(N + 1) * sizeof(int);
    const size_t cnt_b  = (size_t)N * sizeof(int);
    const size_t bsum_b = (size_t)(NB + 1) * sizeof(int);
    const size_t tf_b   = (size_t)N * D * 2;
    auto align_up = [](size_t x) { return (x + 255) & ~(size_t)255; };

    const size_t need_csr  = align_up(ep_b) + align_up(offs_b) + align_up(cnt_b)
                           + 2 * align_up(bsum_b);
    const size_t need_full = need_csr + align_up(tf_b);

    const int gemm_blocks_f32 = (N + TILE_M - 1) / TILE_M;

    if (ws_size >= need_csr) {
        char* p = (char*)d_ws;
        int2*  ep   = (int2*)p;  p += align_up(ep_b);
        int*   offs = (int*)p;   p += align_up(offs_b);
        int*   cnt  = (int*)p;   p += align_up(cnt_b);   // counts, then cursor
        int*   bsum = (int*)p;   p += align_up(bsum_b);
        int*   boff = (int*)p;   p += align_up(bsum_b);
        const bool full = (ws_size >= need_full);
        unsigned short* tf = (unsigned short*)p;

        // CSR build
        hipMemsetAsync(cnt, 0, cnt_b, stream);
        edge_hist<<<(E / 4 + 256) / 256, 256, 0, stream>>>(dst, cnt, E);
        scan_partial<<<NB, 256, 0, stream>>>(cnt, offs, bsum, N);
        scan_block_sums<<<1, 64, 0, stream>>>(bsum, boff, NB);
        add_block_offsets<<<(N + 256) / 256, 256, 0, stream>>>(offs, boff, cnt, N, E);
        edge_bucket_x8<<<8 * 128, 256, 0, stream>>>(src, dst, w, cnt, ep, E, N);

        if (full) {
            // transform-first (linearity): tf = bf16(feat @ W^T), then fused gather+bias+relu
            gemm_bf16<<<(N + 63) / 64, 256, 0, stream>>>(feat, Wm, tf, N);
            csr_gather_bf16<<<(N + 7) / 8, 256, 0, stream>>>(tf, ep, offs, bias, out, N);
        } else {
            csr_gather_f32<<<(N + 7) / 8, 256, 0, stream>>>(feat, ep, offs, out, N);
            node_linear<<<gemm_blocks_f32, 256, 0, stream>>>(out, Wm, bias, out, N);
        }
    } else {
        hipMemsetAsync(out, 0, (size_t)N * D * sizeof(float), stream);
        long long st = (long long)E * 32;
        edge_scatter<<<(int)((st + 255) / 256), 256, 0, stream>>>(feat, src, dst, w, out, E);
        node_linear<<<gemm_blocks_f32, 256, 0, stream>>>(out, Wm, bias, out, N);
    }
}

// Round 5
// 208.356 us; speedup vs baseline: 7.0623x; 1.0213x over previous
//
#include <hip/hip_runtime.h>

#define D 128
#define TILE_M 64
#define BS_STRIDE 129
#define AS_STRIDE 68
#define WS_STRIDE 136   // shorts; 272 B rows -> 16 B aligned, banks spread

typedef __attribute__((ext_vector_type(8))) short short8;
typedef __attribute__((ext_vector_type(4))) float floatx4;
typedef __attribute__((ext_vector_type(4))) unsigned short ushortx4;

__device__ __forceinline__ unsigned short f2bf(float f) {
    unsigned u = __float_as_uint(f);
    u += 0x7fffu + ((u >> 16) & 1u);   // round-to-nearest-even
    return (unsigned short)(u >> 16);
}

// ---------------- MFMA GEMM: tf(bf16) = feat(fp32->bf16) @ W^T ----------------
// W staged fp32->bf16 into LDS per block. 4 waves/block; wave w computes rows
// [m0+16w, m0+16w+16) x 128 cols via 16x16x32 MFMA. Epilogue: D-tile staged
// into LDS (reusing Ws) and written out as coalesced 16B stores (the direct
// C-layout store pattern is 2B x stride-32B scatter -- was the bottleneck).
__global__ __launch_bounds__(256) void gemm_bf16(
    const float* __restrict__ feat, const float* __restrict__ Wm,
    unsigned short* __restrict__ tf, int N)
{
    __shared__ unsigned short Ws[128 * WS_STRIDE];

    const int tid = threadIdx.x;
    // stage W: 4096 float4s, 16 per thread
    for (int idx = tid; idx < 128 * 128 / 4; idx += 256) {
        int r = idx >> 5;
        int c = (idx & 31) * 4;
        const float4 v = reinterpret_cast<const float4*>(Wm)[idx];
        ushortx4 s;
        s[0] = f2bf(v.x); s[1] = f2bf(v.y); s[2] = f2bf(v.z); s[3] = f2bf(v.w);
        *reinterpret_cast<ushortx4*>(&Ws[r * WS_STRIDE + c]) = s;
    }

    const int lane = tid & 63;
    const int wave = tid >> 6;
    const int node0 = blockIdx.x * 64;
    const int m0 = node0 + wave * 16;
    const int mr = m0 + (lane & 15);
    const int kq = (lane >> 4) * 8;

    const float* arow = feat + (size_t)(mr < N ? mr : (N - 1)) * D + kq;

    short8 a[4];
#pragma unroll
    for (int kt = 0; kt < 4; ++kt) {
        const float* p = arow + kt * 32;
        const float4 lo = *reinterpret_cast<const float4*>(p);
        const float4 hi = *reinterpret_cast<const float4*>(p + 4);
        short8 v;
        v[0] = (short)f2bf(lo.x); v[1] = (short)f2bf(lo.y);
        v[2] = (short)f2bf(lo.z); v[3] = (short)f2bf(lo.w);
        v[4] = (short)f2bf(hi.x); v[5] = (short)f2bf(hi.y);
        v[6] = (short)f2bf(hi.z); v[7] = (short)f2bf(hi.w);
        a[kt] = v;
    }

    __syncthreads();

    floatx4 acc[8];
#pragma unroll
    for (int nt = 0; nt < 8; ++nt) {
        acc[nt][0] = 0.f; acc[nt][1] = 0.f; acc[nt][2] = 0.f; acc[nt][3] = 0.f;
    }

#pragma unroll
    for (int nt = 0; nt < 8; ++nt) {
        const unsigned short* brow = &Ws[(nt * 16 + (lane & 15)) * WS_STRIDE + kq];
#pragma unroll
        for (int kt = 0; kt < 4; ++kt) {
            short8 b = *reinterpret_cast<const short8*>(brow + kt * 32);
            acc[nt] = __builtin_amdgcn_mfma_f32_16x16x32_bf16(a[kt], b, acc[nt], 0, 0, 0);
        }
    }

    // ---- epilogue: C-layout -> LDS (reuse Ws) -> coalesced global stores ----
    __syncthreads();   // all waves done reading Ws
    unsigned short* Ds = Ws;   // 64 rows x 128 cols, stride WS_STRIDE
    const int mlocal = wave * 16 + (lane >> 4) * 4;
    const int col = lane & 15;
#pragma unroll
    for (int r = 0; r < 4; ++r) {
        unsigned short* drow = &Ds[(mlocal + r) * WS_STRIDE + col];
#pragma unroll
        for (int nt = 0; nt < 8; ++nt)
            drow[nt * 16] = f2bf(acc[nt][r]);
    }
    __syncthreads();

    // 64 rows x 16 chunks of 16B = 1024 chunks; 4 per thread
    for (int idx = tid; idx < 64 * 16; idx += 256) {
        int row = idx >> 4;
        int chunk = idx & 15;
        int m = node0 + row;
        if (m < N) {
            uint4 v = *reinterpret_cast<const uint4*>(&Ds[row * WS_STRIDE + chunk * 8]);
            *reinterpret_cast<uint4*>(tf + (size_t)m * D + chunk * 8) = v;
        }
    }
}

// ---------------- CSR build ----------------
__global__ __launch_bounds__(256) void edge_hist(
    const int* __restrict__ dst, int* __restrict__ counts, int E)
{
    int e4 = (blockIdx.x * 256 + threadIdx.x) * 4;
    if (e4 + 3 < E) {
        const int4 d = *reinterpret_cast<const int4*>(dst + e4);
        atomicAdd(&counts[d.x], 1);
        atomicAdd(&counts[d.y], 1);
        atomicAdd(&counts[d.z], 1);
        atomicAdd(&counts[d.w], 1);
    } else {
        for (int e = e4; e < E; ++e) atomicAdd(&counts[dst[e]], 1);
    }
}

__global__ __launch_bounds__(256) void scan_partial(
    const int* __restrict__ counts, int* __restrict__ offs,
    int* __restrict__ bsum, int N)
{
    __shared__ int s[256];
    const int tid = threadIdx.x;
    const int base = blockIdx.x * 1024 + tid * 4;
    int c0 = (base + 0 < N) ? counts[base + 0] : 0;
    int c1 = (base + 1 < N) ? counts[base + 1] : 0;
    int c2 = (base + 2 < N) ? counts[base + 2] : 0;
    int c3 = (base + 3 < N) ? counts[base + 3] : 0;
    int t = c0 + c1 + c2 + c3;
    s[tid] = t;
    __syncthreads();
    for (int off = 1; off < 256; off <<= 1) {
        int add = (tid >= off) ? s[tid - off] : 0;
        __syncthreads();
        s[tid] += add;
        __syncthreads();
    }
    int excl = s[tid] - t;
    if (base + 0 < N) offs[base + 0] = excl;
    if (base + 1 < N) offs[base + 1] = excl + c0;
    if (base + 2 < N) offs[base + 2] = excl + c0 + c1;
    if (base + 3 < N) offs[base + 3] = excl + c0 + c1 + c2;
    if (tid == 255) bsum[blockIdx.x] = s[255];
}

__global__ void scan_block_sums(const int* __restrict__ bsum,
                                int* __restrict__ boff, int NB)
{
    __shared__ int s[64];
    const int tid = threadIdx.x;  // 64 threads
    int carry = 0;
    for (int b = 0; b < NB; b += 64) {
        int i = b + tid;
        int v = (i < NB) ? bsum[i] : 0;
        s[tid] = v;
        __syncthreads();
        for (int off = 1; off < 64; off <<= 1) {
            int add = (tid >= off) ? s[tid - off] : 0;
            __syncthreads();
            s[tid] += add;
            __syncthreads();
        }
        int incl = s[tid];
        int tot = s[63];
        if (i < NB) boff[i] = carry + incl - v;
        __syncthreads();
        carry += tot;
    }
}

// also initializes the bucket cursor (replaces d2d copy)
__global__ __launch_bounds__(256) void add_block_offsets(
    int* __restrict__ offs, const int* __restrict__ boff,
    int* __restrict__ cursor, int N, int E)
{
    int i = blockIdx.x * 256 + threadIdx.x;
    if (i < N) {
        int v = offs[i] + boff[i >> 10];
        offs[i] = v;
        cursor[i] = v;
    }
    if (i == N) offs[N] = E;
}

// ---------------- XCD-range-owned bucket scatter ----------------
__global__ __launch_bounds__(256) void edge_bucket_x8(
    const int* __restrict__ src, const int* __restrict__ dst,
    const float* __restrict__ w, int* __restrict__ cursor,
    int2* __restrict__ epack, int E, int N)
{
    const int xcd = blockIdx.x & 7;
    const int blk = blockIdx.x >> 3;
    const int nblk = gridDim.x >> 3;
    const int lo = (int)((long long)xcd * N / 8);
    const int hi = (int)((long long)(xcd + 1) * N / 8);
    for (int e = blk * 256 + threadIdx.x; e < E; e += nblk * 256) {
        int d = dst[e];
        if (d >= lo && d < hi) {
            int pos = atomicAdd(&cursor[d], 1);
            epack[pos] = make_int2(src[e], __float_as_int(w[e]));
        }
    }
}

// ---------------- gather-reduce: out = relu(sum w*tf[src] + b) ----------------
// 16 lanes per node, uint4 (16B = 8 bf16) per lane; 4-edge unroll.
__global__ __launch_bounds__(256) void csr_gather_bf16(
    const unsigned short* __restrict__ tf, const int2* __restrict__ ep,
    const int* __restrict__ offs, const float* __restrict__ bias,
    float* __restrict__ out, int N)
{
    int node = blockIdx.x * 16 + (threadIdx.x >> 4);
    if (node >= N) return;
    const int lane = threadIdx.x & 15;
    const int c = lane << 3;               // 8 bf16 per lane
    int i = offs[node];
    const int end = offs[node + 1];
    float a0 = 0.f, a1 = 0.f, a2 = 0.f, a3 = 0.f;
    float a4 = 0.f, a5 = 0.f, a6 = 0.f, a7 = 0.f;

#define ACC(Q, W)                                        \
    a0 += __uint_as_float((Q).x << 16) * (W);            \
    a1 += __uint_as_float((Q).x & 0xffff0000u) * (W);    \
    a2 += __uint_as_float((Q).y << 16) * (W);            \
    a3 += __uint_as_float((Q).y & 0xffff0000u) * (W);    \
    a4 += __uint_as_float((Q).z << 16) * (W);            \
    a5 += __uint_as_float((Q).z & 0xffff0000u) * (W);    \
    a6 += __uint_as_float((Q).w << 16) * (W);            \
    a7 += __uint_as_float((Q).w & 0xffff0000u) * (W);

    for (; i + 3 < end; i += 4) {
        int2 e0 = ep[i], e1 = ep[i + 1], e2 = ep[i + 2], e3 = ep[i + 3];
        uint4 q0 = *reinterpret_cast<const uint4*>(tf + (size_t)e0.x * D + c);
        uint4 q1 = *reinterpret_cast<const uint4*>(tf + (size_t)e1.x * D + c);
        uint4 q2 = *reinterpret_cast<const uint4*>(tf + (size_t)e2.x * D + c);
        uint4 q3 = *reinterpret_cast<const uint4*>(tf + (size_t)e3.x * D + c);
        float w0 = __int_as_float(e0.y), w1 = __int_as_float(e1.y);
        float w2 = __int_as_float(e2.y), w3 = __int_as_float(e3.y);
        ACC(q0, w0) ACC(q1, w1) ACC(q2, w2) ACC(q3, w3)
    }
    for (; i < end; ++i) {
        int2 e0 = ep[i];
        float w0 = __int_as_float(e0.y);
        uint4 q0 = *reinterpret_cast<const uint4*>(tf + (size_t)e0.x * D + c);
        ACC(q0, w0)
    }
#undef ACC

    const float4 bv0 = *reinterpret_cast<const float4*>(bias + c);
    const float4 bv1 = *reinterpret_cast<const float4*>(bias + c + 4);
    float4 r0, r1;
    r0.x = fmaxf(a0 + bv0.x, 0.f);
    r0.y = fmaxf(a1 + bv0.y, 0.f);
    r0.z = fmaxf(a2 + bv0.z, 0.f);
    r0.w = fmaxf(a3 + bv0.w, 0.f);
    r1.x = fmaxf(a4 + bv1.x, 0.f);
    r1.y = fmaxf(a5 + bv1.y, 0.f);
    r1.z = fmaxf(a6 + bv1.z, 0.f);
    r1.w = fmaxf(a7 + bv1.w, 0.f);
    float* o = out + (size_t)node * D + c;
    *reinterpret_cast<float4*>(o) = r0;
    *reinterpret_cast<float4*>(o + 4) = r1;
}

// ---------------- fp32 gather (fallback path) ----------------
__global__ __launch_bounds__(256) void csr_gather_f32(
    const float* __restrict__ feat, const int2* __restrict__ ep,
    const int* __restrict__ offs, float* __restrict__ out, int N)
{
    int node = blockIdx.x * 8 + (threadIdx.x >> 5);
    if (node >= N) return;
    const int lane = threadIdx.x & 31;
    const int c = lane << 2;
    int i = offs[node];
    const int end = offs[node + 1];
    float a0 = 0.f, a1 = 0.f, a2 = 0.f, a3 = 0.f;
    for (; i < end; ++i) {
        int2 e0 = ep[i];
        float w0 = __int_as_float(e0.y);
        const float4 f = *reinterpret_cast<const float4*>(feat + (size_t)e0.x * D + c);
        a0 += f.x * w0; a1 += f.y * w0; a2 += f.z * w0; a3 += f.w * w0;
    }
    float4 r; r.x = a0; r.y = a1; r.z = a2; r.w = a3;
    *reinterpret_cast<float4*>(out + (size_t)node * D + c) = r;
}

// ---------------- fp32 vector GEMM (fallback): out = relu(in @ W^T + b) ----
__global__ __launch_bounds__(256) void node_linear(
    const float* __restrict__ in, const float* __restrict__ Wm,
    const float* __restrict__ bias, float* __restrict__ out, int N)
{
    __shared__ float Bs[64 * BS_STRIDE];
    __shared__ float As[TILE_M * AS_STRIDE];
    const int tid = threadIdx.x;
    const int tx = tid & 15;
    const int ty = tid >> 4;
    const int node0 = blockIdx.x * TILE_M;
    float acc[4][8];
#pragma unroll
    for (int i = 0; i < 4; ++i)
#pragma unroll
        for (int jj = 0; jj < 8; ++jj) acc[i][jj] = 0.0f;
    for (int kh = 0; kh < 2; ++kh) {
        const int kbase = kh * 64;
        for (int i = tid; i < 128 * 64; i += 256) {
            int j = i >> 6, k = i & 63;
            Bs[k * BS_STRIDE + j] = Wm[j * 128 + kbase + k];
        }
        for (int i = tid; i < TILE_M * 64; i += 256) {
            int m = i >> 6, k = i & 63;
            int n = node0 + m;
            As[m * AS_STRIDE + k] = (n < N) ? in[(size_t)n * D + kbase + k] : 0.0f;
        }
        __syncthreads();
        for (int k0 = 0; k0 < 64; k0 += 4) {
            float a[4][4];
#pragma unroll
            for (int i = 0; i < 4; ++i) {
                const float4 v = *reinterpret_cast<const float4*>(&As[(ty * 4 + i) * AS_STRIDE + k0]);
                a[i][0] = v.x; a[i][1] = v.y; a[i][2] = v.z; a[i][3] = v.w;
            }
#pragma unroll
            for (int kk = 0; kk < 4; ++kk) {
                float bv[8];
#pragma unroll
                for (int jj = 0; jj < 8; ++jj) bv[jj] = Bs[(k0 + kk) * BS_STRIDE + tx + 16 * jj];
#pragma unroll
                for (int i = 0; i < 4; ++i)
#pragma unroll
                    for (int jj = 0; jj < 8; ++jj) acc[i][jj] += a[i][kk] * bv[jj];
            }
        }
        __syncthreads();
    }
    float bv[8];
#pragma unroll
    for (int jj = 0; jj < 8; ++jj) bv[jj] = bias[tx + 16 * jj];
#pragma unroll
    for (int i = 0; i < 4; ++i) {
        int n = node0 + ty * 4 + i;
        if (n < N) {
            float* o = out + (size_t)n * D;
#pragma unroll
            for (int jj = 0; jj < 8; ++jj) {
                float v = acc[i][jj] + bv[jj];
                o[tx + 16 * jj] = v > 0.0f ? v : 0.0f;
            }
        }
    }
}

// ---------------- tier-1 fallback: atomic scatter ----------------
__global__ __launch_bounds__(256) void edge_scatter(
    const float* __restrict__ feat, const int* __restrict__ src,
    const int* __restrict__ dst, const float* __restrict__ w,
    float* __restrict__ agg, int E)
{
    long long idx = (long long)blockIdx.x * 256 + threadIdx.x;
    int e = (int)(idx >> 5);
    if (e >= E) return;
    int c = ((int)idx & 31) << 2;
    int s = src[e];
    int d = dst[e];
    float wv = w[e];
    const float4 f = *reinterpret_cast<const float4*>(feat + (size_t)s * D + c);
    float* a = agg + (size_t)d * D + c;
    atomicAdd(a + 0, f.x * wv);
    atomicAdd(a + 1, f.y * wv);
    atomicAdd(a + 2, f.z * wv);
    atomicAdd(a + 3, f.w * wv);
}

extern "C" void kernel_launch(void* const* d_in, const int* in_sizes, int n_in,
                              void* d_out, int out_size, void* d_ws, size_t ws_size,
                              hipStream_t stream) {
    const float* feat = (const float*)d_in[0];
    const int*   src  = (const int*)d_in[1];
    const int*   dst  = (const int*)d_in[2];
    const float* w    = (const float*)d_in[3];
    const float* Wm   = (const float*)d_in[4];
    const float* bias = (const float*)d_in[5];
    float* out = (float*)d_out;

    const int N = in_sizes[0] / D;   // 50000
    const int E = in_sizes[1];       // 800000
    const int NB = (N + 1023) / 1024;

    const size_t ep_b   = (size_t)E * 8;
    const size_t offs_b = (size_t)(N + 1) * sizeof(int);
    const size_t cnt_b  = (size_t)N * sizeof(int);
    const size_t bsum_b = (size_t)(NB + 1) * sizeof(int);
    const size_t tf_b   = (size_t)N * D * 2;
    auto align_up = [](size_t x) { return (x + 255) & ~(size_t)255; };

    const size_t need_csr  = align_up(ep_b) + align_up(offs_b) + align_up(cnt_b)
                           + 2 * align_up(bsum_b);
    const size_t need_full = need_csr + align_up(tf_b);

    const int gemm_blocks_f32 = (N + TILE_M - 1) / TILE_M;

    if (ws_size >= need_csr) {
        char* p = (char*)d_ws;
        int2*  ep   = (int2*)p;  p += align_up(ep_b);
        int*   offs = (int*)p;   p += align_up(offs_b);
        int*   cnt  = (int*)p;   p += align_up(cnt_b);   // counts, then cursor
        int*   bsum = (int*)p;   p += align_up(bsum_b);
        int*   boff = (int*)p;   p += align_up(bsum_b);
        const bool full = (ws_size >= need_full);
        unsigned short* tf = (unsigned short*)p;

        // CSR build
        hipMemsetAsync(cnt, 0, cnt_b, stream);
        edge_hist<<<(E / 4 + 256) / 256, 256, 0, stream>>>(dst, cnt, E);
        scan_partial<<<NB, 256, 0, stream>>>(cnt, offs, bsum, N);
        scan_block_sums<<<1, 64, 0, stream>>>(bsum, boff, NB);
        add_block_offsets<<<(N + 256) / 256, 256, 0, stream>>>(offs, boff, cnt, N, E);
        edge_bucket_x8<<<8 * 256, 256, 0, stream>>>(src, dst, w, cnt, ep, E, N);

        if (full) {
            // transform-first (linearity): tf = bf16(feat @ W^T), then fused gather+bias+relu
            gemm_bf16<<<(N + 63) / 64, 256, 0, stream>>>(feat, Wm, tf, N);
            csr_gather_bf16<<<(N + 15) / 16, 256, 0, stream>>>(tf, ep, offs, bias, out, N);
        } else {
            csr_gather_f32<<<(N + 7) / 8, 256, 0, stream>>>(feat, ep, offs, out, N);
            node_linear<<<gemm_blocks_f32, 256, 0, stream>>>(out, Wm, bias, out, N);
        }
    } else {
        hipMemsetAsync(out, 0, (size_t)N * D * sizeof(float), stream);
        long long st = (long long)E * 32;
        edge_scatter<<<(int)((st + 255) / 256), 256, 0, stream>>>(feat, src, dst, w, out, E);
        node_linear<<<gemm_blocks_f32, 256, 0, stream>>>(out, Wm, bias, out, N);
    }
}